// Round 16
// baseline (174.861 us; speedup 1.0000x reference)
//
#include <hip/hip_runtime.h>
#include <hip/hip_bf16.h>

#define NBUCK 8192
#define P1B   64        // pass1 blocks per image
#define CAP   4096
#define TOPN  2000
#define NP2   2048
#define OUTN  1000
#define NST   64        // chunks (32 rows each)
#define NSLOT 8         // LDS slots (8 KB each)
#define SLOTW 2048      // words per slot

typedef unsigned int u32x4 __attribute__((ext_vector_type(4)));
typedef __attribute__((address_space(1))) const unsigned GUP;
typedef __attribute__((address_space(3))) unsigned LUP;

__device__ __forceinline__ float4 decode_box(const float4 a, const float4 d, float W, float H) {
    float aw = a.z - a.x;
    float ah = a.w - a.y;
    float ax = a.x + 0.5f * aw;
    float ay = a.y + 0.5f * ah;
    float dw = fminf(d.z, 4.135f);
    float dh = fminf(d.w, 4.135f);
    float px = d.x * aw + ax;
    float py = d.y * ah + ay;
    float pw = expf(dw) * aw;
    float ph = expf(dh) * ah;
    float4 r;
    r.x = fminf(fmaxf(px - 0.5f * pw, 0.0f), W);
    r.y = fminf(fmaxf(py - 0.5f * ph, 0.0f), H);
    r.z = fminf(fmaxf(px + 0.5f * pw, 0.0f), W);
    r.w = fminf(fmaxf(py + 0.5f * ph, 0.0f), H);
    return r;
}

__device__ __forceinline__ unsigned score_key(const float4 a, const float4 d, float W, float H, float s) {
    float4 b = decode_box(a, d, W, H);
    bool ok = ((b.z - b.x) >= 4.0f) && ((b.w - b.y) >= 4.0f);
    float ms = ok ? s : -INFINITY;
    unsigned u = __float_as_uint(ms);
    return (u & 0x80000000u) ? ~u : (u | 0x80000000u);
}

// K1: compute+store keys; single 32KB LDS hist; per-block hist as packed u16
// (plain 16B stores, NO global atomics). Also re-inits cnt/remInit/done.
__global__ void __launch_bounds__(1024) k_pass1(const float* __restrict__ pred,
        const float* __restrict__ obj, const float* __restrict__ anch,
        const int* __restrict__ Hp, const int* __restrict__ Wp,
        unsigned* __restrict__ keys, unsigned short* __restrict__ bhist,
        unsigned* __restrict__ cnt, unsigned* __restrict__ remInit,
        unsigned* __restrict__ done, int N) {
    __shared__ unsigned h[NBUCK];   // 32 KB
    int t = threadIdx.x;
    int b = blockIdx.y, g = blockIdx.x;
    if (g == 0 && t < 64) {
        if (t == 0) { cnt[b * 64] = 0; done[b] = 0; }
        remInit[b * 64 + t] = 0;
    }
    for (int i = t; i < NBUCK; i += 1024) h[i] = 0;
    __syncthreads();
    int chunk = (N + P1B - 1) / P1B;       // 3907 (< 65536 -> u16-safe)
    int base = g * chunk;
    int end = base + chunk; if (end > N) end = N;
    float W = (float)*Wp, H = (float)*Hp;
    for (int n = base + t; n < end; n += 1024) {
        float4 a = ((const float4*)anch)[n];
        float4 d = ((const float4*)pred)[(size_t)b * N + n];
        float s = obj[(size_t)b * N + n];
        unsigned key = score_key(a, d, W, H, s);
        keys[(size_t)b * N + n] = key;
        atomicAdd(&h[key >> 19], 1u);
    }
    __syncthreads();
    unsigned short* bh = bhist + ((size_t)(b * P1B + g)) * NBUCK;
    int i0 = t * 8;
    uint4 pk;
    pk.x = (h[i0 + 0] & 0xFFFFu) | (h[i0 + 1] << 16);
    pk.y = (h[i0 + 2] & 0xFFFFu) | (h[i0 + 3] << 16);
    pk.z = (h[i0 + 4] & 0xFFFFu) | (h[i0 + 5] << 16);
    pk.w = (h[i0 + 6] & 0xFFFFu) | (h[i0 + 7] << 16);
    *(uint4*)(bh + i0) = pk;
}

// K2: fused scan. Grid (8,B)x1024. Phase A: block p merges buckets
// [p*1024, p*1024+1024) of the 64 u16 sub-hists -> hist32 (coalesced 2KB reads).
// Last-block-per-image handoff (done counter, threadfence precedent: R10 mega,
// bit-correct on this chip) runs the suffix-scan -> Lb; also re-inits sdone.
__global__ void __launch_bounds__(1024) k_scan(const unsigned short* __restrict__ bhist,
        unsigned* __restrict__ hist32, unsigned* __restrict__ done,
        unsigned* __restrict__ Lb, unsigned* __restrict__ sdone) {
    __shared__ unsigned h[NBUCK];
    __shared__ unsigned csum[256];
    __shared__ unsigned suf[256];
    __shared__ int tcS;
    __shared__ unsigned befS;
    __shared__ int lastFlag;
    int b = blockIdx.y, p = blockIdx.x, t = threadIdx.x;
    int bkt = p * 1024 + t;
    const unsigned short* src = bhist + (size_t)b * P1B * NBUCK + bkt;
    unsigned acc = 0;
    #pragma unroll 8
    for (int g = 0; g < P1B; g++) acc += src[(size_t)g * NBUCK];
    hist32[b * NBUCK + bkt] = acc;
    __threadfence();
    __syncthreads();
    if (t == 0) {
        unsigned d = __hip_atomic_fetch_add(&done[b], 1u, __ATOMIC_ACQ_REL,
                                            __HIP_MEMORY_SCOPE_AGENT);
        lastFlag = (d == 7);
        if (d == 7) sdone[b] = 0;
    }
    __syncthreads();
    if (!lastFlag) return;
    __threadfence();
    // ---- scan phase (1024 threads; R12-P2 proven body) ----
    for (int i = t; i < NBUCK; i += 1024)
        h[i] = __hip_atomic_load(&hist32[b * NBUCK + i], __ATOMIC_RELAXED,
                                 __HIP_MEMORY_SCOPE_AGENT);
    if (t == 0) tcS = -1;
    __syncthreads();
    if (t < 256) {
        unsigned s = 0;
        for (int j = 0; j < 32; j++) s += h[t * 32 + j];
        csum[t] = s; suf[t] = s;
    }
    __syncthreads();
    for (int d = 1; d < 256; d <<= 1) {
        unsigned v = (t < 256 && t + d < 256) ? suf[t + d] : 0;
        __syncthreads();
        if (t < 256) suf[t] += v;
        __syncthreads();
    }
    if (t < 256 && suf[t] >= (unsigned)TOPN && (t == 255 || suf[t + 1] < (unsigned)TOPN)) {
        tcS = t; befS = (t == 255) ? 0u : suf[t + 1];
    }
    __syncthreads();
    if (t == 0) {
        unsigned L = 0;
        int tc = tcS;
        if (tc >= 0) {
            unsigned r = befS;
            for (int bkt2 = tc * 32 + 31;; bkt2--) {
                r += h[bkt2];
                if (r >= (unsigned)TOPN || bkt2 == tc * 32) { L = (unsigned)bkt2; break; }
            }
        }
        Lb[b] = L;
    }
}

// K3: collect candidates from precomputed keys; LDS-aggregated, 1 global atomic/block
__global__ void k_collect(const unsigned* __restrict__ keys, const unsigned* __restrict__ Lb,
                          unsigned* __restrict__ count, unsigned long long* __restrict__ cand,
                          int N) {
    __shared__ unsigned lk[1024], ln[1024];
    __shared__ unsigned lcnt, lbase;
    int b = blockIdx.y, t = threadIdx.x;
    if (t == 0) lcnt = 0;
    __syncthreads();
    unsigned L = Lb[b];
    const unsigned* kb = keys + (size_t)b * N;
    int e = blockIdx.x * 256 + t;
    int n0 = e * 4;
    if (n0 + 3 < N) {
        uint4 kv = ((const uint4*)kb)[e];
        if ((kv.x >> 19) >= L) { unsigned p = atomicAdd(&lcnt, 1u); lk[p] = kv.x; ln[p] = n0; }
        if ((kv.y >> 19) >= L) { unsigned p = atomicAdd(&lcnt, 1u); lk[p] = kv.y; ln[p] = n0 + 1; }
        if ((kv.z >> 19) >= L) { unsigned p = atomicAdd(&lcnt, 1u); lk[p] = kv.z; ln[p] = n0 + 2; }
        if ((kv.w >> 19) >= L) { unsigned p = atomicAdd(&lcnt, 1u); lk[p] = kv.w; ln[p] = n0 + 3; }
    } else {
        for (int j = 0; j < 4; j++) {
            int n = n0 + j;
            if (n < N) {
                unsigned k = kb[n];
                if ((k >> 19) >= L) { unsigned p = atomicAdd(&lcnt, 1u); lk[p] = k; ln[p] = n; }
            }
        }
    }
    __syncthreads();
    if (t == 0) lbase = atomicAdd(&count[b * 64], lcnt);
    __syncthreads();
    unsigned c = lcnt, bs = lbase;
    for (unsigned i = t; i < c; i += 256) {
        unsigned pos = bs + i;
        if (pos < CAP) cand[(size_t)b * CAP + pos] =
            ((unsigned long long)lk[i] << 32) | (unsigned)(~ln[i]);
    }
}

// Register compare-exchange for one shuffle pass
#define REGX(e, p, d, lo)  ((lo) == (d) ? ((e) >= (p) ? (e) : (p)) : ((e) >= (p) ? (p) : (e)))

// K4: fused sort. Grid B*8 x 1024. Phase 1: 512-chunk bitonic sort (threads
// 0..255, R10-P4 proven structure; all-zero chunks early-out). Last-block-
// per-image handoff runs the 1024-thread merge (R11 fast/slow) + gather.
__global__ void __launch_bounds__(1024) k_sort(unsigned long long* __restrict__ cand,
        const unsigned* __restrict__ count, unsigned* __restrict__ sdone,
        const float* __restrict__ pred, const float* __restrict__ anch,
        const int* __restrict__ Hp, const int* __restrict__ Wp,
        float4* __restrict__ topbox, unsigned* __restrict__ remInit, int N) {
    __shared__ unsigned long long s[CAP];   // 32 KB (phase1 uses first 512)
    __shared__ int lastFlag;
    int b = blockIdx.x >> 3, g = blockIdx.x & 7;
    int t = threadIdx.x;
    unsigned cnt = count[b * 64]; if (cnt > CAP) cnt = CAP;
    unsigned long long* cb = cand + (size_t)b * CAP + g * 512;

    // ---- phase 1: sort1 ----
    if ((unsigned)(g * 512) >= cnt) {
        if (t < 256) { cb[t] = 0ULL; cb[t + 256] = 0ULL; }
    } else {
        int g0 = g * 512 + t, g1 = g * 512 + t + 256;
        unsigned long long e0 = 0, e1 = 0;
        if (t < 256) {
            e0 = (g0 < (int)cnt) ? cb[t] : 0ULL;
            e1 = (g1 < (int)cnt) ? cb[t + 256] : 0ULL;
            #pragma unroll
            for (int k = 2; k <= 64; k <<= 1) {
                bool d0 = ((g0 & k) == 0);
                bool d1 = ((g1 & k) == 0);
                #pragma unroll
                for (int j = k >> 1; j >= 1; j >>= 1) {
                    bool lo = ((t & j) == 0);
                    unsigned long long p0 = __shfl_xor(e0, j, 64);
                    unsigned long long p1 = __shfl_xor(e1, j, 64);
                    e0 = REGX(e0, p0, d0, lo);
                    e1 = REGX(e1, p1, d1, lo);
                }
            }
        }
        for (int k = 128; k <= 512; k <<= 1) {
            if (t < 256) { s[t] = e0; s[t + 256] = e1; }
            __syncthreads();
            for (int j = k >> 1; j >= 64; j >>= 1) {
                if (t < 256) {
                    int i = ((t & ~(j - 1)) << 1) | (t & (j - 1));
                    int l = i + j;
                    bool desc = (((g * 512 + i) & k) == 0);
                    unsigned long long x = s[i], y = s[l];
                    if (desc ? (x < y) : (x > y)) { s[i] = y; s[l] = x; }
                }
                __syncthreads();
            }
            if (t < 256) {
                e0 = s[t]; e1 = s[t + 256];
                bool d0 = ((g0 & k) == 0);
                bool d1 = ((g1 & k) == 0);
                #pragma unroll
                for (int j = 32; j >= 1; j >>= 1) {
                    bool lo = ((t & j) == 0);
                    unsigned long long p0 = __shfl_xor(e0, j, 64);
                    unsigned long long p1 = __shfl_xor(e1, j, 64);
                    e0 = REGX(e0, p0, d0, lo);
                    e1 = REGX(e1, p1, d1, lo);
                }
            }
        }
        if (t < 256) { cb[t] = e0; cb[t + 256] = e1; }
    }

    // ---- handoff ----
    __threadfence();
    __syncthreads();
    if (t == 0) {
        unsigned d = __hip_atomic_fetch_add(&sdone[b], 1u, __ATOMIC_ACQ_REL,
                                            __HIP_MEMORY_SCOPE_AGENT);
        lastFlag = (d == 7);
    }
    __syncthreads();
    if (!lastFlag) return;
    __threadfence();

    // ---- phase 2: merge + gather (1024 threads, R11 proven body) ----
    const unsigned long long* cbb = cand + (size_t)b * CAP;
    unsigned long long e0, e1;
    if (cnt <= 2048) {
        e0 = cbb[t]; e1 = cbb[t + 1024];
        for (int k = 1024; k <= 2048; k <<= 1) {
            s[t] = e0; s[t + 1024] = e1;
            __syncthreads();
            for (int j = k >> 1; j >= 64; j >>= 1) {
                int i = ((t & ~(j - 1)) << 1) | (t & (j - 1));
                int l = i + j;
                bool desc = ((i & k) == 0);
                unsigned long long x = s[i], y = s[l];
                if (desc ? (x < y) : (x > y)) { s[i] = y; s[l] = x; }
                __syncthreads();
            }
            e0 = s[t]; e1 = s[t + 1024];
            bool d0 = ((t & k) == 0);
            bool d1 = (((t + 1024) & k) == 0);
            #pragma unroll
            for (int j = 32; j >= 1; j >>= 1) {
                bool lo = ((t & j) == 0);
                unsigned long long p0 = __shfl_xor(e0, j, 64);
                unsigned long long p1 = __shfl_xor(e1, j, 64);
                e0 = REGX(e0, p0, d0, lo);
                e1 = REGX(e1, p1, d1, lo);
            }
        }
    } else {
        unsigned long long f0 = cbb[t], f1 = cbb[t + 1024], f2 = cbb[t + 2048], f3 = cbb[t + 3072];
        for (int k = 1024; k <= 4096; k <<= 1) {
            s[t] = f0; s[t + 1024] = f1; s[t + 2048] = f2; s[t + 3072] = f3;
            __syncthreads();
            for (int j = k >> 1; j >= 64; j >>= 1) {
                #pragma unroll
                for (int cc = 0; cc < 2; cc++) {
                    int c = t + cc * 1024;
                    int i = ((c & ~(j - 1)) << 1) | (c & (j - 1));
                    int l = i + j;
                    bool desc = ((i & k) == 0);
                    unsigned long long x = s[i], y = s[l];
                    if (desc ? (x < y) : (x > y)) { s[i] = y; s[l] = x; }
                }
                __syncthreads();
            }
            f0 = s[t]; f1 = s[t + 1024]; f2 = s[t + 2048]; f3 = s[t + 3072];
            bool d0 = ((t & k) == 0);
            bool d1 = (((t + 1024) & k) == 0);
            bool d2 = (((t + 2048) & k) == 0);
            bool d3 = (((t + 3072) & k) == 0);
            #pragma unroll
            for (int j = 32; j >= 1; j >>= 1) {
                bool lo = ((t & j) == 0);
                unsigned long long p0 = __shfl_xor(f0, j, 64);
                unsigned long long p1 = __shfl_xor(f1, j, 64);
                unsigned long long p2 = __shfl_xor(f2, j, 64);
                unsigned long long p3 = __shfl_xor(f3, j, 64);
                f0 = REGX(f0, p0, d0, lo);
                f1 = REGX(f1, p1, d1, lo);
                f2 = REGX(f2, p2, d2, lo);
                f3 = REGX(f3, p3, d3, lo);
            }
        }
        e0 = f0; e1 = f1;
    }
    float W = (float)*Wp, H = (float)*Hp;
    #pragma unroll
    for (int m = 0; m < 2; m++) {
        unsigned long long v = m ? e1 : e0;
        int r = t + m * 1024;
        unsigned key = (unsigned)(v >> 32);
        bool valid = key > 0x007FFFFFu;
        float4 outb = {0.f, 0.f, 0.f, 0.f};
        if (valid) {
            unsigned idx = ~((unsigned)v);
            float4 a = ((const float4*)anch)[idx];
            float4 d = ((const float4*)pred)[(size_t)b * N + idx];
            outb = decode_box(a, d, W, H);
        }
        topbox[(size_t)b * NP2 + r] = outb;
        if (r < TOPN && !valid) atomicOr(&remInit[b * 64 + (r >> 5)], 1u << (r & 31));
    }
}

// K5: suppression bitmask, transposed layout, triangle-pruned + load-balanced
__global__ void __launch_bounds__(256) k_mask(const float4* __restrict__ topbox,
                                              unsigned* __restrict__ maskT) {
    const double MID = 23488103.0 / 33554432.0;
    __shared__ float4 bx[NP2];
    __shared__ float ar[NP2];
    int b = blockIdx.y, cp = blockIdx.x;   // cp in 0..31
    int t = threadIdx.x;
    int j0 = cp * 32;
    for (int i = j0 + t; i < NP2; i += 256) {
        float4 v = topbox[(size_t)b * NP2 + i];
        bx[i] = v;
        ar[i] = (v.z - v.x) * (v.w - v.y);
    }
    __syncthreads();
    int r = t & 31;
    int wg = t >> 5;
    #pragma unroll
    for (int half = 0; half < 2; half++) {
        int c = half ? (63 - cp) : cp;
        int i = c * 32 + r;
        float4 bi = bx[i];
        float areai = ar[i];
        unsigned* outc = maskT + ((size_t)(b * NST + c)) * SLOTW;
        for (int w = wg; w < c; w += 8) outc[w * 32 + r] = 0u;
        for (int w = c + wg; w < 64; w += 8) {
            unsigned bits = 0;
            int jbase = w * 32;
            #pragma unroll
            for (int jj = 0; jj < 32; jj++) {
                int j = jbase + jj;
                float4 bj = bx[j];
                float iw = fmaxf(fminf(bi.z, bj.z) - fmaxf(bi.x, bj.x), 0.0f);
                float ih = fmaxf(fminf(bi.w, bj.w) - fmaxf(bi.y, bj.y), 0.0f);
                float inter = iw * ih;
                float denom = areai + ar[j] - inter + 1e-9f;
                if ((double)inter >= MID * (double)denom) bits |= (1u << jj);
            }
            if (w == c) bits &= ~((2u << r) - 1u);
            outc[w * 32 + r] = bits;
        }
    }
}

// K6: producer-consumer serial NMS, DMA staging + swizzled LDS + early exit.
__global__ void __launch_bounds__(512) k_nms(const unsigned* __restrict__ maskT,
        const unsigned* __restrict__ remInit, const float4* __restrict__ topbox,
        float* __restrict__ out, int B) {
    __shared__ __align__(16) unsigned smbuf[NSLOT * SLOTW];   // 64 KB
    __shared__ int ready[NST];
    __shared__ int consumed;
    __shared__ int stop;
    int b = blockIdx.x;
    int t = threadIdx.x;
    const unsigned* m = maskT + (size_t)b * NST * SLOTW;

    float4* ob = (float4*)out + (size_t)b * OUTN;
    for (int i = t; i < OUTN; i += 512) ob[i] = make_float4(0.f, 0.f, 0.f, 0.f);
    float* vout = out + (size_t)B * (OUTN * 4) + (size_t)b * OUTN;
    for (int i = t; i < OUTN; i += 512) vout[i] = 0.0f;

    if (t < NST) ready[t] = 0;
    if (t == 0) { consumed = 0; stop = 0; }
    __syncthreads();

    unsigned removed = 0xFFFFFFFFu;

    if (t >= 64) {
        int w = t >> 6;
        int lam = t & 63;
        int base = ((lam >> 3) << 5) + ((((lam & 7) ^ ((lam >> 3) & 7))) << 2);
        #pragma unroll 1
        for (int s = w - 1; s < NST; s += 7) {
            if (__hip_atomic_load(&stop, __ATOMIC_RELAXED, __HIP_MEMORY_SCOPE_WORKGROUP)) break;
            while (__hip_atomic_load(&consumed, __ATOMIC_ACQUIRE,
                   __HIP_MEMORY_SCOPE_WORKGROUP) < s - (NSLOT - 1))
                __builtin_amdgcn_s_sleep(2);
            const unsigned* gs = m + (size_t)s * SLOTW + base;
            unsigned* sl = smbuf + (s & (NSLOT - 1)) * SLOTW;
            #pragma unroll
            for (int i = 0; i < 8; i++)
                __builtin_amdgcn_global_load_lds((GUP*)(gs + i * 256),
                                                 (LUP*)(sl + i * 256), 16, 0, 0);
            asm volatile("s_waitcnt vmcnt(0)" ::: "memory");
            if (lam == 0) __hip_atomic_store(&ready[s], 1, __ATOMIC_RELEASE,
                                             __HIP_MEMORY_SCOPE_WORKGROUP);
        }
    } else {
        removed = remInit[b * 64 + t];
        if (t == 62) removed |= 0xFFFF0000u;   // ranks 2000..2015
        if (t == 63) removed = 0xFFFFFFFFu;    // ranks 2016..2047
        int e = t & 7;
        int keptRun = 0;
        #pragma unroll 1
        for (int s = 0; s < NST; s++) {
            while (!__hip_atomic_load(&ready[s], __ATOMIC_ACQUIRE,
                   __HIP_MEMORY_SCOPE_WORKGROUP))
                __builtin_amdgcn_s_sleep(2);
            const u32x4* sq = (const u32x4*)(smbuf + (s & (NSLOT - 1)) * SLOTW) + t * 8;
            unsigned R[32];
            #pragma unroll
            for (int k = 0; k < 8; k++) *(u32x4*)&R[k << 2] = sq[k ^ e];
            __builtin_amdgcn_sched_group_barrier(0x100, 8, 0);  // cluster the 8 ds_reads
            unsigned alive = ~__builtin_amdgcn_readlane(removed, s);
            unsigned Is[32];
            #pragma unroll
            for (int q = 0; q < 32; q++) Is[q] = __builtin_amdgcn_readlane(R[q], s);
            #pragma unroll
            for (int q = 0; q < 32; q++) alive &= ~(((alive >> q) & 1u) ? Is[q] : 0u);
            unsigned a0 = 0, a1 = 0, a2 = 0, a3 = 0;
            #pragma unroll
            for (int q = 0; q < 32; q += 4) {
                a0 |= ((alive >> q) & 1u)       ? R[q]     : 0u;
                a1 |= ((alive >> (q + 1)) & 1u) ? R[q + 1] : 0u;
                a2 |= ((alive >> (q + 2)) & 1u) ? R[q + 2] : 0u;
                a3 |= ((alive >> (q + 3)) & 1u) ? R[q + 3] : 0u;
            }
            removed |= (a0 | a1) | (a2 | a3);
            keptRun += __popc(~__builtin_amdgcn_readlane(removed, s));
            if (keptRun >= OUTN) {
                if (t == 0) {
                    __hip_atomic_store(&stop, 1, __ATOMIC_RELAXED, __HIP_MEMORY_SCOPE_WORKGROUP);
                    __hip_atomic_store(&consumed, NST, __ATOMIC_RELEASE, __HIP_MEMORY_SCOPE_WORKGROUP);
                }
                break;
            }
            if (t == 0) __hip_atomic_store(&consumed, s + 1, __ATOMIC_RELEASE,
                                           __HIP_MEMORY_SCOPE_WORKGROUP);
        }
        unsigned keep = ~removed;
        int cnt = __popc(keep);
        int ex = cnt;
        for (int off = 1; off < 64; off <<= 1) {
            int v = __shfl_up(ex, off, 64);
            if (t >= off) ex += v;
        }
        ex -= cnt;
        int pos = ex;
        for (int j = 0; j < 32; j++) {
            if ((keep >> j) & 1u) {
                if (pos < OUTN) {
                    float4 bxv = topbox[(size_t)b * NP2 + t * 32 + j];
                    ob[pos] = bxv;
                    vout[pos] = 1.0f;
                }
                pos++;
            }
        }
    }
}

extern "C" void kernel_launch(void* const* d_in, const int* in_sizes, int n_in,
                              void* d_out, int out_size, void* d_ws, size_t ws_size,
                              hipStream_t stream) {
    const float* pred = (const float*)d_in[0];
    const float* obj  = (const float*)d_in[1];
    const float* anch = (const float*)d_in[2];
    const int* Hp = (const int*)d_in[3];
    const int* Wp = (const int*)d_in[4];
    int N = in_sizes[2] / 4;           // 250000
    int B = in_sizes[1] / N;           // 8

    char* ws = (char*)d_ws;
    size_t off = 0;
    auto take = [&](size_t bytes) { void* p = ws + off; off = (off + bytes + 255) & ~(size_t)255; return p; };

    // Region A: keys (k_pass1..k_collect), reused as maskT (k_mask..k_nms)
    size_t regA_bytes = (size_t)B * N * 4;                       // 8.0 MB
    size_t mask_bytes = (size_t)B * NST * SLOTW * 4;             // 4.2 MB (< regA)
    char* regA = (char*)take(regA_bytes > mask_bytes ? regA_bytes : mask_bytes);
    unsigned* keys  = (unsigned*)regA;
    unsigned* maskT = (unsigned*)regA;
    unsigned short* bhist    = (unsigned short*)take((size_t)B * P1B * NBUCK * 2);  // 8 MB
    unsigned* hist32         = (unsigned*)take((size_t)B * NBUCK * 4);              // 256 KB
    unsigned long long* cand = (unsigned long long*)take((size_t)B * CAP * 8);
    float4* topbox           = (float4*)take((size_t)B * NP2 * 16);
    unsigned* cnt            = (unsigned*)take((size_t)B * 64 * 4);
    unsigned* Lb             = (unsigned*)take((size_t)B * 64 * 4);
    unsigned* remInit        = (unsigned*)take((size_t)B * 64 * 4);
    unsigned* done           = (unsigned*)take((size_t)B * 4);
    unsigned* sdone          = (unsigned*)take((size_t)B * 4);

    k_pass1  <<<dim3(P1B, B), 1024, 0, stream>>>(pred, obj, anch, Hp, Wp, keys, bhist, cnt, remInit, done, N);
    k_scan   <<<dim3(8, B), 1024, 0, stream>>>(bhist, hist32, done, Lb, sdone);
    k_collect<<<dim3((N + 1023) / 1024, B), 256, 0, stream>>>(keys, Lb, cnt, cand, N);
    k_sort   <<<B * 8, 1024, 0, stream>>>(cand, cnt, sdone, pred, anch, Hp, Wp, topbox, remInit, N);
    k_mask   <<<dim3(32, B), 256, 0, stream>>>(topbox, maskT);
    k_nms    <<<B, 512, 0, stream>>>(maskT, remInit, topbox, (float*)d_out, B);
}

// Round 17
// 112.165 us; speedup vs baseline: 1.5590x; 1.5590x over previous
//
#include <hip/hip_runtime.h>
#include <hip/hip_bf16.h>

#define NBUCK 8192
#define P1B   64        // pass1 blocks per image
#define CAP   4096
#define TOPN  2000
#define NP2   2048
#define OUTN  1000
#define NST   64        // chunks (32 rows each)
#define NSLOT 8         // LDS slots (8 KB each)
#define SLOTW 2048      // words per slot

typedef unsigned int u32x4 __attribute__((ext_vector_type(4)));
typedef __attribute__((address_space(1))) const unsigned GUP;
typedef __attribute__((address_space(3))) unsigned LUP;

__device__ __forceinline__ float4 decode_box(const float4 a, const float4 d, float W, float H) {
    float aw = a.z - a.x;
    float ah = a.w - a.y;
    float ax = a.x + 0.5f * aw;
    float ay = a.y + 0.5f * ah;
    float dw = fminf(d.z, 4.135f);
    float dh = fminf(d.w, 4.135f);
    float px = d.x * aw + ax;
    float py = d.y * ah + ay;
    float pw = expf(dw) * aw;
    float ph = expf(dh) * ah;
    float4 r;
    r.x = fminf(fmaxf(px - 0.5f * pw, 0.0f), W);
    r.y = fminf(fmaxf(py - 0.5f * ph, 0.0f), H);
    r.z = fminf(fmaxf(px + 0.5f * pw, 0.0f), W);
    r.w = fminf(fmaxf(py + 0.5f * ph, 0.0f), H);
    return r;
}

__device__ __forceinline__ unsigned score_key(const float4 a, const float4 d, float W, float H, float s) {
    float4 b = decode_box(a, d, W, H);
    bool ok = ((b.z - b.x) >= 4.0f) && ((b.w - b.y) >= 4.0f);
    float ms = ok ? s : -INFINITY;
    unsigned u = __float_as_uint(ms);
    return (u & 0x80000000u) ? ~u : (u | 0x80000000u);
}

// K1: compute+store keys; single 32KB LDS hist (2 blocks/CU); per-block hist
// stored as packed u16 (plain 16B stores, NO global atomics).
__global__ void __launch_bounds__(1024) k_pass1(const float* __restrict__ pred,
        const float* __restrict__ obj, const float* __restrict__ anch,
        const int* __restrict__ Hp, const int* __restrict__ Wp,
        unsigned* __restrict__ keys, unsigned short* __restrict__ bhist,
        unsigned* __restrict__ cnt, unsigned* __restrict__ remInit, int N) {
    __shared__ unsigned h[NBUCK];   // 32 KB
    int t = threadIdx.x;
    int b = blockIdx.y, g = blockIdx.x;
    if (g == 0 && t < 64) { if (t == 0) cnt[b * 64] = 0; remInit[b * 64 + t] = 0; }
    for (int i = t; i < NBUCK; i += 1024) h[i] = 0;
    __syncthreads();
    int chunk = (N + P1B - 1) / P1B;       // 3907 (< 65536 -> u16-safe)
    int base = g * chunk;
    int end = base + chunk; if (end > N) end = N;
    float W = (float)*Wp, H = (float)*Hp;
    for (int n = base + t; n < end; n += 1024) {
        float4 a = ((const float4*)anch)[n];
        float4 d = ((const float4*)pred)[(size_t)b * N + n];
        float s = obj[(size_t)b * N + n];
        unsigned key = score_key(a, d, W, H, s);
        keys[(size_t)b * N + n] = key;
        atomicAdd(&h[key >> 19], 1u);
    }
    __syncthreads();
    // pack 8 consecutive buckets per thread into one 16B store (coalesced)
    unsigned short* bh = bhist + ((size_t)(b * P1B + g)) * NBUCK;
    int i0 = t * 8;
    uint4 pk;
    pk.x = (h[i0 + 0] & 0xFFFFu) | (h[i0 + 1] << 16);
    pk.y = (h[i0 + 2] & 0xFFFFu) | (h[i0 + 3] << 16);
    pk.z = (h[i0 + 4] & 0xFFFFu) | (h[i0 + 5] << 16);
    pk.w = (h[i0 + 6] & 0xFFFFu) | (h[i0 + 7] << 16);
    *(uint4*)(bh + i0) = pk;
}

// K2a: parallel merge of the 64 u16 sub-hists -> u32 hist32.
// Grid (8, B): block p of image b merges buckets [p*1024, p*1024+1024).
__global__ void __launch_bounds__(1024) k_scanA(const unsigned short* __restrict__ bhist,
                                                unsigned* __restrict__ hist32) {
    int b = blockIdx.y, p = blockIdx.x, t = threadIdx.x;
    int bkt = p * 1024 + t;
    const unsigned short* src = bhist + (size_t)b * P1B * NBUCK + bkt;
    unsigned acc = 0;
    #pragma unroll 8
    for (int g = 0; g < P1B; g++) acc += src[(size_t)g * NBUCK];
    hist32[b * NBUCK + bkt] = acc;
}

// K2b: suffix-scan u32 hist to find boundary bucket L per image
__global__ void k_scanB(const unsigned* __restrict__ hist32, unsigned* __restrict__ Lb) {
    __shared__ unsigned h[NBUCK];
    __shared__ unsigned csum[256];
    __shared__ unsigned suf[256];
    __shared__ int tcS;
    __shared__ unsigned befS;
    int b = blockIdx.x, t = threadIdx.x;
    const unsigned* src = hist32 + (size_t)b * NBUCK;
    for (int i = t * 4; i < NBUCK; i += 1024) {
        uint4 v = *(const uint4*)(src + i);
        h[i] = v.x; h[i + 1] = v.y; h[i + 2] = v.z; h[i + 3] = v.w;
    }
    if (t == 0) tcS = -1;
    __syncthreads();
    unsigned s = 0;
    for (int j = 0; j < 32; j++) s += h[t * 32 + j];
    csum[t] = s; suf[t] = s;
    __syncthreads();
    for (int d = 1; d < 256; d <<= 1) {
        unsigned v = (t + d < 256) ? suf[t + d] : 0;
        __syncthreads();
        suf[t] += v;
        __syncthreads();
    }
    if (suf[t] >= (unsigned)TOPN && (t == 255 || suf[t + 1] < (unsigned)TOPN)) {
        tcS = t; befS = (t == 255) ? 0u : suf[t + 1];
    }
    __syncthreads();
    if (t == 0) {
        unsigned L = 0;
        int tc = tcS;
        if (tc >= 0) {
            unsigned r = befS;
            for (int bkt = tc * 32 + 31;; bkt--) {
                r += h[bkt];
                if (r >= (unsigned)TOPN || bkt == tc * 32) { L = (unsigned)bkt; break; }
            }
        }
        Lb[b] = L;
    }
}

// K3: collect candidates from precomputed keys; LDS-aggregated, 1 global atomic/block
__global__ void k_collect(const unsigned* __restrict__ keys, const unsigned* __restrict__ Lb,
                          unsigned* __restrict__ count, unsigned long long* __restrict__ cand,
                          int N) {
    __shared__ unsigned lk[1024], ln[1024];
    __shared__ unsigned lcnt, lbase;
    int b = blockIdx.y, t = threadIdx.x;
    if (t == 0) lcnt = 0;
    __syncthreads();
    unsigned L = Lb[b];
    const unsigned* kb = keys + (size_t)b * N;
    int e = blockIdx.x * 256 + t;
    int n0 = e * 4;
    if (n0 + 3 < N) {
        uint4 kv = ((const uint4*)kb)[e];
        if ((kv.x >> 19) >= L) { unsigned p = atomicAdd(&lcnt, 1u); lk[p] = kv.x; ln[p] = n0; }
        if ((kv.y >> 19) >= L) { unsigned p = atomicAdd(&lcnt, 1u); lk[p] = kv.y; ln[p] = n0 + 1; }
        if ((kv.z >> 19) >= L) { unsigned p = atomicAdd(&lcnt, 1u); lk[p] = kv.z; ln[p] = n0 + 2; }
        if ((kv.w >> 19) >= L) { unsigned p = atomicAdd(&lcnt, 1u); lk[p] = kv.w; ln[p] = n0 + 3; }
    } else {
        for (int j = 0; j < 4; j++) {
            int n = n0 + j;
            if (n < N) {
                unsigned k = kb[n];
                if ((k >> 19) >= L) { unsigned p = atomicAdd(&lcnt, 1u); lk[p] = k; ln[p] = n; }
            }
        }
    }
    __syncthreads();
    if (t == 0) lbase = atomicAdd(&count[b * 64], lcnt);
    __syncthreads();
    unsigned c = lcnt, bs = lbase;
    for (unsigned i = t; i < c; i += 256) {
        unsigned pos = bs + i;
        if (pos < CAP) cand[(size_t)b * CAP + pos] =
            ((unsigned long long)lk[i] << 32) | (unsigned)(~ln[i]);
    }
}

// Register compare-exchange for one shuffle pass
#define REGX(e, p, d, lo)  ((lo) == (d) ? ((e) >= (p) ? (e) : (p)) : ((e) >= (p) ? (p) : (e)))

// K4a: bitonic sort of 512-entry chunks (8/image); all-zero chunks early-out
__global__ void __launch_bounds__(256) k_sort1(unsigned long long* __restrict__ cand,
        const unsigned* __restrict__ count) {
    __shared__ unsigned long long s[512];
    int b = blockIdx.x >> 3, g = blockIdx.x & 7;
    int t = threadIdx.x;
    unsigned cnt = count[b * 64]; if (cnt > CAP) cnt = CAP;
    unsigned long long* cb = cand + (size_t)b * CAP + g * 512;
    if ((unsigned)(g * 512) >= cnt) {
        cb[t] = 0ULL; cb[t + 256] = 0ULL;
        return;
    }
    int g0 = g * 512 + t, g1 = g * 512 + t + 256;
    unsigned long long e0 = (g0 < (int)cnt) ? cb[t] : 0ULL;
    unsigned long long e1 = (g1 < (int)cnt) ? cb[t + 256] : 0ULL;

    #pragma unroll
    for (int k = 2; k <= 64; k <<= 1) {
        bool d0 = ((g0 & k) == 0);
        bool d1 = ((g1 & k) == 0);
        #pragma unroll
        for (int j = k >> 1; j >= 1; j >>= 1) {
            bool lo = ((t & j) == 0);
            unsigned long long p0 = __shfl_xor(e0, j, 64);
            unsigned long long p1 = __shfl_xor(e1, j, 64);
            e0 = REGX(e0, p0, d0, lo);
            e1 = REGX(e1, p1, d1, lo);
        }
    }
    for (int k = 128; k <= 512; k <<= 1) {
        s[t] = e0; s[t + 256] = e1;
        __syncthreads();
        for (int j = k >> 1; j >= 64; j >>= 1) {
            int i = ((t & ~(j - 1)) << 1) | (t & (j - 1));
            int l = i + j;
            bool desc = (((g * 512 + i) & k) == 0);
            unsigned long long x = s[i], y = s[l];
            if (desc ? (x < y) : (x > y)) { s[i] = y; s[l] = x; }
            __syncthreads();
        }
        e0 = s[t]; e1 = s[t + 256];
        bool d0 = ((g0 & k) == 0);
        bool d1 = ((g1 & k) == 0);
        #pragma unroll
        for (int j = 32; j >= 1; j >>= 1) {
            bool lo = ((t & j) == 0);
            unsigned long long p0 = __shfl_xor(e0, j, 64);
            unsigned long long p1 = __shfl_xor(e1, j, 64);
            e0 = REGX(e0, p0, d0, lo);
            e1 = REGX(e1, p1, d1, lo);
        }
    }
    cb[t] = e0; cb[t + 256] = e1;
}

// K4b: merge + fused gather/decode + remInit (fast path cnt<=2048)
__global__ void __launch_bounds__(1024) k_sort2(const unsigned long long* __restrict__ cand,
        const unsigned* __restrict__ count,
        const float* __restrict__ pred, const float* __restrict__ anch,
        const int* __restrict__ Hp, const int* __restrict__ Wp,
        float4* __restrict__ topbox, unsigned* __restrict__ remInit, int N) {
    __shared__ unsigned long long s[CAP];
    int b = blockIdx.x, t = threadIdx.x;
    const unsigned long long* cb = cand + (size_t)b * CAP;
    unsigned cnt = count[b * 64]; if (cnt > CAP) cnt = CAP;
    unsigned long long e0, e1;
    if (cnt <= 2048) {
        e0 = cb[t]; e1 = cb[t + 1024];
        for (int k = 1024; k <= 2048; k <<= 1) {
            s[t] = e0; s[t + 1024] = e1;
            __syncthreads();
            for (int j = k >> 1; j >= 64; j >>= 1) {
                int i = ((t & ~(j - 1)) << 1) | (t & (j - 1));
                int l = i + j;
                bool desc = ((i & k) == 0);
                unsigned long long x = s[i], y = s[l];
                if (desc ? (x < y) : (x > y)) { s[i] = y; s[l] = x; }
                __syncthreads();
            }
            e0 = s[t]; e1 = s[t + 1024];
            bool d0 = ((t & k) == 0);
            bool d1 = (((t + 1024) & k) == 0);
            #pragma unroll
            for (int j = 32; j >= 1; j >>= 1) {
                bool lo = ((t & j) == 0);
                unsigned long long p0 = __shfl_xor(e0, j, 64);
                unsigned long long p1 = __shfl_xor(e1, j, 64);
                e0 = REGX(e0, p0, d0, lo);
                e1 = REGX(e1, p1, d1, lo);
            }
        }
    } else {
        unsigned long long f0 = cb[t], f1 = cb[t + 1024], f2 = cb[t + 2048], f3 = cb[t + 3072];
        for (int k = 1024; k <= 4096; k <<= 1) {
            s[t] = f0; s[t + 1024] = f1; s[t + 2048] = f2; s[t + 3072] = f3;
            __syncthreads();
            for (int j = k >> 1; j >= 64; j >>= 1) {
                #pragma unroll
                for (int cc = 0; cc < 2; cc++) {
                    int c = t + cc * 1024;
                    int i = ((c & ~(j - 1)) << 1) | (c & (j - 1));
                    int l = i + j;
                    bool desc = ((i & k) == 0);
                    unsigned long long x = s[i], y = s[l];
                    if (desc ? (x < y) : (x > y)) { s[i] = y; s[l] = x; }
                }
                __syncthreads();
            }
            f0 = s[t]; f1 = s[t + 1024]; f2 = s[t + 2048]; f3 = s[t + 3072];
            bool d0 = ((t & k) == 0);
            bool d1 = (((t + 1024) & k) == 0);
            bool d2 = (((t + 2048) & k) == 0);
            bool d3 = (((t + 3072) & k) == 0);
            #pragma unroll
            for (int j = 32; j >= 1; j >>= 1) {
                bool lo = ((t & j) == 0);
                unsigned long long p0 = __shfl_xor(f0, j, 64);
                unsigned long long p1 = __shfl_xor(f1, j, 64);
                unsigned long long p2 = __shfl_xor(f2, j, 64);
                unsigned long long p3 = __shfl_xor(f3, j, 64);
                f0 = REGX(f0, p0, d0, lo);
                f1 = REGX(f1, p1, d1, lo);
                f2 = REGX(f2, p2, d2, lo);
                f3 = REGX(f3, p3, d3, lo);
            }
        }
        e0 = f0; e1 = f1;
    }
    float W = (float)*Wp, H = (float)*Hp;
    #pragma unroll
    for (int m = 0; m < 2; m++) {
        unsigned long long v = m ? e1 : e0;
        int r = t + m * 1024;
        unsigned key = (unsigned)(v >> 32);
        bool valid = key > 0x007FFFFFu;
        float4 outb = {0.f, 0.f, 0.f, 0.f};
        if (valid) {
            unsigned idx = ~((unsigned)v);
            float4 a = ((const float4*)anch)[idx];
            float4 d = ((const float4*)pred)[(size_t)b * N + idx];
            outb = decode_box(a, d, W, H);
        }
        topbox[(size_t)b * NP2 + r] = outb;
        if (r < TOPN && !valid) atomicOr(&remInit[b * 64 + (r >> 5)], 1u << (r & 31));
    }
}

// K5: suppression bitmask, transposed layout, triangle-pruned + load-balanced.
// 512 threads/block (wg 0..15, word-stride 16): halves per-block critical path.
__global__ void __launch_bounds__(512) k_mask(const float4* __restrict__ topbox,
                                              unsigned* __restrict__ maskT) {
    const double MID = 23488103.0 / 33554432.0;
    __shared__ float4 bx[NP2];
    __shared__ float ar[NP2];
    int b = blockIdx.y, cp = blockIdx.x;   // cp in 0..31
    int t = threadIdx.x;
    int j0 = cp * 32;
    for (int i = j0 + t; i < NP2; i += 512) {
        float4 v = topbox[(size_t)b * NP2 + i];
        bx[i] = v;
        ar[i] = (v.z - v.x) * (v.w - v.y);
    }
    __syncthreads();
    int r = t & 31;
    int wg = t >> 5;                      // 0..15
    #pragma unroll
    for (int half = 0; half < 2; half++) {
        int c = half ? (63 - cp) : cp;
        int i = c * 32 + r;
        float4 bi = bx[i];
        float areai = ar[i];
        unsigned* outc = maskT + ((size_t)(b * NST + c)) * SLOTW;
        for (int w = wg; w < c; w += 16) outc[w * 32 + r] = 0u;
        for (int w = c + wg; w < 64; w += 16) {
            unsigned bits = 0;
            int jbase = w * 32;
            #pragma unroll
            for (int jj = 0; jj < 32; jj++) {
                int j = jbase + jj;
                float4 bj = bx[j];
                float iw = fmaxf(fminf(bi.z, bj.z) - fmaxf(bi.x, bj.x), 0.0f);
                float ih = fmaxf(fminf(bi.w, bj.w) - fmaxf(bi.y, bj.y), 0.0f);
                float inter = iw * ih;
                float denom = areai + ar[j] - inter + 1e-9f;
                if ((double)inter >= MID * (double)denom) bits |= (1u << jj);
            }
            if (w == c) bits &= ~((2u << r) - 1u);
            outc[w * 32 + r] = bits;
        }
    }
}

// K6: producer-consumer serial NMS, DMA staging + swizzled LDS + early exit.
__global__ void __launch_bounds__(512) k_nms(const unsigned* __restrict__ maskT,
        const unsigned* __restrict__ remInit, const float4* __restrict__ topbox,
        float* __restrict__ out, int B) {
    __shared__ __align__(16) unsigned smbuf[NSLOT * SLOTW];   // 64 KB
    __shared__ int ready[NST];
    __shared__ int consumed;
    __shared__ int stop;
    int b = blockIdx.x;
    int t = threadIdx.x;
    const unsigned* m = maskT + (size_t)b * NST * SLOTW;

    float4* ob = (float4*)out + (size_t)b * OUTN;
    for (int i = t; i < OUTN; i += 512) ob[i] = make_float4(0.f, 0.f, 0.f, 0.f);
    float* vout = out + (size_t)B * (OUTN * 4) + (size_t)b * OUTN;
    for (int i = t; i < OUTN; i += 512) vout[i] = 0.0f;

    if (t < NST) ready[t] = 0;
    if (t == 0) { consumed = 0; stop = 0; }
    __syncthreads();

    unsigned removed = 0xFFFFFFFFu;

    if (t >= 64) {
        int w = t >> 6;
        int lam = t & 63;
        int base = ((lam >> 3) << 5) + ((((lam & 7) ^ ((lam >> 3) & 7))) << 2);
        #pragma unroll 1
        for (int s = w - 1; s < NST; s += 7) {
            if (__hip_atomic_load(&stop, __ATOMIC_RELAXED, __HIP_MEMORY_SCOPE_WORKGROUP)) break;
            while (__hip_atomic_load(&consumed, __ATOMIC_ACQUIRE,
                   __HIP_MEMORY_SCOPE_WORKGROUP) < s - (NSLOT - 1))
                __builtin_amdgcn_s_sleep(2);
            const unsigned* gs = m + (size_t)s * SLOTW + base;
            unsigned* sl = smbuf + (s & (NSLOT - 1)) * SLOTW;
            #pragma unroll
            for (int i = 0; i < 8; i++)
                __builtin_amdgcn_global_load_lds((GUP*)(gs + i * 256),
                                                 (LUP*)(sl + i * 256), 16, 0, 0);
            asm volatile("s_waitcnt vmcnt(0)" ::: "memory");
            if (lam == 0) __hip_atomic_store(&ready[s], 1, __ATOMIC_RELEASE,
                                             __HIP_MEMORY_SCOPE_WORKGROUP);
        }
    } else {
        removed = remInit[b * 64 + t];
        if (t == 62) removed |= 0xFFFF0000u;   // ranks 2000..2015
        if (t == 63) removed = 0xFFFFFFFFu;    // ranks 2016..2047
        int e = t & 7;
        int keptRun = 0;
        #pragma unroll 1
        for (int s = 0; s < NST; s++) {
            while (!__hip_atomic_load(&ready[s], __ATOMIC_ACQUIRE,
                   __HIP_MEMORY_SCOPE_WORKGROUP))
                __builtin_amdgcn_s_sleep(2);
            const u32x4* sq = (const u32x4*)(smbuf + (s & (NSLOT - 1)) * SLOTW) + t * 8;
            unsigned R[32];
            #pragma unroll
            for (int k = 0; k < 8; k++) *(u32x4*)&R[k << 2] = sq[k ^ e];
            __builtin_amdgcn_sched_group_barrier(0x100, 8, 0);  // cluster the 8 ds_reads
            unsigned alive = ~__builtin_amdgcn_readlane(removed, s);
            unsigned Is[32];
            #pragma unroll
            for (int q = 0; q < 32; q++) Is[q] = __builtin_amdgcn_readlane(R[q], s);
            #pragma unroll
            for (int q = 0; q < 32; q++) alive &= ~(((alive >> q) & 1u) ? Is[q] : 0u);
            unsigned a0 = 0, a1 = 0, a2 = 0, a3 = 0;
            #pragma unroll
            for (int q = 0; q < 32; q += 4) {
                a0 |= ((alive >> q) & 1u)       ? R[q]     : 0u;
                a1 |= ((alive >> (q + 1)) & 1u) ? R[q + 1] : 0u;
                a2 |= ((alive >> (q + 2)) & 1u) ? R[q + 2] : 0u;
                a3 |= ((alive >> (q + 3)) & 1u) ? R[q + 3] : 0u;
            }
            removed |= (a0 | a1) | (a2 | a3);
            keptRun += __popc(~__builtin_amdgcn_readlane(removed, s));
            if (keptRun >= OUTN) {
                if (t == 0) {
                    __hip_atomic_store(&stop, 1, __ATOMIC_RELAXED, __HIP_MEMORY_SCOPE_WORKGROUP);
                    __hip_atomic_store(&consumed, NST, __ATOMIC_RELEASE, __HIP_MEMORY_SCOPE_WORKGROUP);
                }
                break;
            }
            if (t == 0) __hip_atomic_store(&consumed, s + 1, __ATOMIC_RELEASE,
                                           __HIP_MEMORY_SCOPE_WORKGROUP);
        }
        unsigned keep = ~removed;
        int cnt = __popc(keep);
        int ex = cnt;
        for (int off = 1; off < 64; off <<= 1) {
            int v = __shfl_up(ex, off, 64);
            if (t >= off) ex += v;
        }
        ex -= cnt;
        int pos = ex;
        for (int j = 0; j < 32; j++) {
            if ((keep >> j) & 1u) {
                if (pos < OUTN) {
                    float4 bxv = topbox[(size_t)b * NP2 + t * 32 + j];
                    ob[pos] = bxv;
                    vout[pos] = 1.0f;
                }
                pos++;
            }
        }
    }
}

extern "C" void kernel_launch(void* const* d_in, const int* in_sizes, int n_in,
                              void* d_out, int out_size, void* d_ws, size_t ws_size,
                              hipStream_t stream) {
    const float* pred = (const float*)d_in[0];
    const float* obj  = (const float*)d_in[1];
    const float* anch = (const float*)d_in[2];
    const int* Hp = (const int*)d_in[3];
    const int* Wp = (const int*)d_in[4];
    int N = in_sizes[2] / 4;           // 250000
    int B = in_sizes[1] / N;           // 8

    char* ws = (char*)d_ws;
    size_t off = 0;
    auto take = [&](size_t bytes) { void* p = ws + off; off = (off + bytes + 255) & ~(size_t)255; return p; };

    // Region A: keys (k_pass1..k_collect), reused as maskT (k_mask..k_nms)
    size_t regA_bytes = (size_t)B * N * 4;                       // 8.0 MB
    size_t mask_bytes = (size_t)B * NST * SLOTW * 4;             // 4.2 MB (< regA)
    char* regA = (char*)take(regA_bytes > mask_bytes ? regA_bytes : mask_bytes);
    unsigned* keys  = (unsigned*)regA;
    unsigned* maskT = (unsigned*)regA;
    unsigned short* bhist    = (unsigned short*)take((size_t)B * P1B * NBUCK * 2);  // 8 MB
    unsigned* hist32         = (unsigned*)take((size_t)B * NBUCK * 4);              // 256 KB
    unsigned long long* cand = (unsigned long long*)take((size_t)B * CAP * 8);
    float4* topbox           = (float4*)take((size_t)B * NP2 * 16);
    unsigned* cnt            = (unsigned*)take((size_t)B * 64 * 4);
    unsigned* Lb             = (unsigned*)take((size_t)B * 64 * 4);
    unsigned* remInit        = (unsigned*)take((size_t)B * 64 * 4);

    k_pass1  <<<dim3(P1B, B), 1024, 0, stream>>>(pred, obj, anch, Hp, Wp, keys, bhist, cnt, remInit, N);
    k_scanA  <<<dim3(8, B), 1024, 0, stream>>>(bhist, hist32);
    k_scanB  <<<B, 256, 0, stream>>>(hist32, Lb);
    k_collect<<<dim3((N + 1023) / 1024, B), 256, 0, stream>>>(keys, Lb, cnt, cand, N);
    k_sort1  <<<B * 8, 256, 0, stream>>>(cand, cnt);
    k_sort2  <<<B, 1024, 0, stream>>>(cand, cnt, pred, anch, Hp, Wp, topbox, remInit, N);
    k_mask   <<<dim3(32, B), 512, 0, stream>>>(topbox, maskT);
    k_nms    <<<B, 512, 0, stream>>>(maskT, remInit, topbox, (float*)d_out, B);
}